// Round 9
// baseline (373.544 us; speedup 1.0000x reference)
//
#include <hip/hip_runtime.h>
#include <math.h>

// GATNet: N=100000 nodes, D=128, HEADS=4, HID=32, OUT_C=64, E=1.6M (+N self-loops)
#define NEG_SLOPE 0.2f
#define BK_SHIFT 8          // bucket = dst >> 8 (256 dsts per bucket)

typedef __attribute__((ext_vector_type(2))) float v2f;
typedef __attribute__((ext_vector_type(8))) short bf16x8;   // 8 bf16 = 4 VGPRs
typedef __attribute__((ext_vector_type(4))) float f32x4;

__device__ __forceinline__ float leaky(float x) { return x > 0.f ? x : NEG_SLOPE * x; }
// fp32 -> bf16 round-to-nearest-even
__device__ __forceinline__ unsigned short f2bf(float f) {
    unsigned int x = __float_as_uint(f);
    unsigned int r = (x + 0x7fffu + ((x >> 16) & 1u)) >> 16;
    return (unsigned short)r;
}
__device__ __forceinline__ float bflo(unsigned int u) { return __uint_as_float(u << 16); }
__device__ __forceinline__ float bfhi(unsigned int u) { return __uint_as_float(u & 0xffff0000u); }

// ---------------- prep: W1 hi/lo + W2 B-fragment packs, bcounts zero ----------------

__global__ void __launch_bounds__(256) prep_kernel(const float* __restrict__ W1,
                                                   const float* __restrict__ W2,
                                                   unsigned short* __restrict__ w1ph,
                                                   unsigned short* __restrict__ w1pl,
                                                   unsigned short* __restrict__ w2p,
                                                   int* __restrict__ bcounts) {
    int i = blockIdx.x * 256 + threadIdx.x;
    if (i < 16384) {
        int j = i & 7, l = (i >> 3) & 63, c = (i >> 9) & 7, t = i >> 12;
        int k = t * 32 + ((l >> 4) << 3) + j;
        int col = c * 16 + (l & 15);
        float v = W1[k * 128 + col];
        unsigned short hi = f2bf(v);
        w1ph[i] = hi;
        w1pl[i] = f2bf(v - __uint_as_float((unsigned)hi << 16));
    } else if (i < 16384 + 8192) {
        int i2 = i - 16384;
        int t = i2 >> 11, c = (i2 >> 9) & 3, l = (i2 >> 3) & 63, j = i2 & 7;
        int k = t * 32 + (l >> 4) * 8 + j;
        int col = c * 16 + (l & 15);
        w2p[i2] = f2bf(W2[k * 64 + col]);
    } else if (i < 16384 + 8192 + 512) {
        bcounts[i - 16384 - 8192] = 0;
    }
}

// ---------------- CSR build: dst-radix partition ----------------

__global__ void __launch_bounds__(256) bcount_kernel(const int* __restrict__ ei, int E, int E2,
                                                     int K, int* __restrict__ bcounts) {
    __shared__ int h[512];
    int t = threadIdx.x;
    h[t] = 0; h[t + 256] = 0;
    __syncthreads();
    int base = blockIdx.x * 4096;
#pragma unroll 4
    for (int i = 0; i < 16; i++) {
        int e = base + i * 256 + t;
        if (e < E2) {
            int dst = (e < E) ? ei[E + e] : (e - E);
            atomicAdd(&h[dst >> BK_SHIFT], 1);
        }
    }
    __syncthreads();
    for (int b = t; b < K; b += 256) {
        int c = h[b];
        if (c) atomicAdd(&bcounts[b], c);
    }
}

__global__ void __launch_bounds__(512) bscan_kernel(const int* __restrict__ bcounts, int K,
                                                    int* __restrict__ bbase, int* __restrict__ bcursor) {
    __shared__ int s[512];
    int t = threadIdx.x;
    int v = (t < K) ? bcounts[t] : 0;
    s[t] = v;
    __syncthreads();
    for (int off = 1; off < 512; off <<= 1) {
        int u = (t >= off) ? s[t - off] : 0;
        __syncthreads();
        s[t] += u;
        __syncthreads();
    }
    if (t < K) {
        int ex = s[t] - v;
        bbase[t] = ex;
        bcursor[t] = ex;
    }
    if (t == 511) bbase[K] = s[511];
}

// stage packed (src<<8 | dstLow8) + u16 bin tag; copy out in coalesced runs
__global__ void __launch_bounds__(256) bscatter_kernel(const int* __restrict__ ei, int E, int E2,
                                                       int K, int* __restrict__ bcursor,
                                                       unsigned int* __restrict__ bedges) {
    __shared__ int hist[512], pre[512], lcur[512], gbase[512], psum[256];
    __shared__ unsigned int stage[4096];
    __shared__ unsigned short binof[4096];
    int t = threadIdx.x;
    hist[t] = 0; hist[t + 256] = 0;
    __syncthreads();
    int base = blockIdx.x * 4096;
    int cnt = min(4096, E2 - base);
    int s_[16], d_[16];
#pragma unroll
    for (int i = 0; i < 16; i++) {
        int e = base + i * 256 + t;
        if (e < E2) {
            int ss, dd;
            if (e < E) { ss = ei[e]; dd = ei[E + e]; }
            else       { ss = e - E; dd = ss; }
            s_[i] = ss; d_[i] = dd;
            atomicAdd(&hist[dd >> BK_SHIFT], 1);
        }
    }
    __syncthreads();
    int a0 = hist[2 * t], a1 = hist[2 * t + 1];
    psum[t] = a0 + a1;
    __syncthreads();
    for (int off = 1; off < 256; off <<= 1) {
        int u = (t >= off) ? psum[t - off] : 0;
        __syncthreads();
        psum[t] += u;
        __syncthreads();
    }
    int pex = psum[t] - (a0 + a1);
    pre[2 * t] = pex;
    pre[2 * t + 1] = pex + a0;
    __syncthreads();
    for (int b = t; b < K; b += 256) {
        int c = hist[b];
        if (c) gbase[b] = atomicAdd(&bcursor[b], c);
    }
    lcur[t] = pre[t]; lcur[t + 256] = pre[t + 256];
    __syncthreads();
#pragma unroll
    for (int i = 0; i < 16; i++) {
        int e = base + i * 256 + t;
        if (e < E2) {
            int bin = d_[i] >> BK_SHIFT;
            int p = atomicAdd(&lcur[bin], 1);
            stage[p] = ((unsigned)s_[i] << 8) | (unsigned)(d_[i] & 255);
            binof[p] = (unsigned short)bin;
        }
    }
    __syncthreads();
    for (int i = t; i < cnt; i += 256) {
        unsigned int ed = stage[i];
        int bin = (int)binof[i];
        bedges[gbase[bin] + (i - pre[bin])] = ed;
    }
}

__global__ void __launch_bounds__(256) bcsr_kernel(const unsigned int* __restrict__ bedges,
                                                   const int* __restrict__ bbase, int N,
                                                   int* __restrict__ counts, int* __restrict__ indptr,
                                                   int* __restrict__ csr) {
    __shared__ int hist[256], scn[256], cur[256];
    int b = blockIdx.x;
    int t = threadIdx.x;
    int base = bbase[b];
    int cnt = bbase[b + 1] - base;
    hist[t] = 0;
    __syncthreads();
    for (int i = t; i < cnt; i += 256) {
        atomicAdd(&hist[bedges[base + i] & 255u], 1);
    }
    __syncthreads();
    int v = hist[t];
    scn[t] = v;
    __syncthreads();
    for (int off = 1; off < 256; off <<= 1) {
        int u = (t >= off) ? scn[t - off] : 0;
        __syncthreads();
        scn[t] += u;
        __syncthreads();
    }
    int ex = scn[t] - v;
    int d = (b << BK_SHIFT) + t;
    if (d < N) { counts[d] = v; indptr[d] = base + ex; }
    cur[t] = ex;
    __syncthreads();
    for (int i = t; i < cnt; i += 256) {
        unsigned int ed = bedges[base + i];
        int p = atomicAdd(&cur[ed & 255u], 1);
        csr[base + p] = (int)(ed >> 8);
    }
}

// ---------------- gemm1 on MFMA: bf16x3 split (near-fp32), fused alpha1 ----------------

__global__ __launch_bounds__(256) void gemm1_kernel(const float* __restrict__ emb,
                             const int* __restrict__ xidx,
                             const unsigned short* __restrict__ w1ph,
                             const unsigned short* __restrict__ w1pl,
                             unsigned short* __restrict__ h1b,
                             const float* __restrict__ a_s1, const float* __restrict__ a_d1,
                             float* __restrict__ as1, float* __restrict__ ad1, int N) {
    __shared__ __attribute__((aligned(16))) unsigned short w1s[2][16384];   // 64 KB
    int tid = threadIdx.x;
    {
        const uint4* h4 = (const uint4*)w1ph;
        const uint4* l4 = (const uint4*)w1pl;
        uint4* sh = (uint4*)w1s[0];
        uint4* sl = (uint4*)w1s[1];
        for (int i = tid; i < 2048; i += 256) { sh[i] = h4[i]; sl[i] = l4[i]; }
    }
    __syncthreads();
    int lane = tid & 63;
    int wv = tid >> 6;
    int l15 = lane & 15;
    int kb = lane >> 4;
    int r0 = blockIdx.x * 128 + wv * 32;
    int sA[2];
#pragma unroll
    for (int rt = 0; rt < 2; rt++) {
        int r = r0 + rt * 16 + l15;
        sA[rt] = xidx[min(r, N - 1)];
    }
    f32x4 acc[2][8];
#pragma unroll
    for (int rt = 0; rt < 2; rt++)
#pragma unroll
        for (int c = 0; c < 8; c++) acc[rt][c] = (f32x4){0.f, 0.f, 0.f, 0.f};

#pragma unroll
    for (int t = 0; t < 4; t++) {
        bf16x8 ahi[2], alo[2];
#pragma unroll
        for (int rt = 0; rt < 2; rt++) {
            const float* ap = emb + (size_t)sA[rt] * 128 + t * 32 + kb * 8;
            float4 a0 = *(const float4*)ap;
            float4 a1 = *(const float4*)(ap + 4);
            float av[8] = {a0.x, a0.y, a0.z, a0.w, a1.x, a1.y, a1.z, a1.w};
#pragma unroll
            for (int j = 0; j < 8; j++) {
                unsigned short hi = f2bf(av[j]);
                ahi[rt][j] = (short)hi;
                alo[rt][j] = (short)f2bf(av[j] - __uint_as_float((unsigned)hi << 16));
            }
        }
#pragma unroll
        for (int c = 0; c < 8; c++) {
            bf16x8 bhi = *(const bf16x8*)&w1s[0][((t * 8 + c) * 64 + lane) * 8];
            bf16x8 blo = *(const bf16x8*)&w1s[1][((t * 8 + c) * 64 + lane) * 8];
#pragma unroll
            for (int rt = 0; rt < 2; rt++) {
                acc[rt][c] = __builtin_amdgcn_mfma_f32_16x16x32_bf16(ahi[rt], bhi, acc[rt][c], 0, 0, 0);
                acc[rt][c] = __builtin_amdgcn_mfma_f32_16x16x32_bf16(alo[rt], bhi, acc[rt][c], 0, 0, 0);
                acc[rt][c] = __builtin_amdgcn_mfma_f32_16x16x32_bf16(ahi[rt], blo, acc[rt][c], 0, 0, 0);
            }
        }
    }
    // epilogue: h1 bf16 stores + alpha dots from C-regs
    float asv[8], adv[8];
#pragma unroll
    for (int c = 0; c < 8; c++) {
        asv[c] = a_s1[c * 16 + l15];     // flat [head*32+hid] == col index
        adv[c] = a_d1[c * 16 + l15];
    }
#pragma unroll
    for (int rt = 0; rt < 2; rt++) {
#pragma unroll
        for (int reg = 0; reg < 4; reg++) {
            int row = r0 + rt * 16 + kb * 4 + reg;
            bool vr = row < N;
            if (vr) {
#pragma unroll
                for (int c = 0; c < 8; c++)
                    h1b[(size_t)row * 128 + c * 16 + l15] = f2bf(acc[rt][c][reg]);
            }
            float ps[4], pd[4];
#pragma unroll
            for (int h = 0; h < 4; h++) {
                ps[h] = acc[rt][2 * h][reg] * asv[2 * h] + acc[rt][2 * h + 1][reg] * asv[2 * h + 1];
                pd[h] = acc[rt][2 * h][reg] * adv[2 * h] + acc[rt][2 * h + 1][reg] * adv[2 * h + 1];
            }
#pragma unroll
            for (int off = 1; off <= 8; off <<= 1) {
#pragma unroll
                for (int h = 0; h < 4; h++) {
                    ps[h] += __shfl_xor(ps[h], off);
                    pd[h] += __shfl_xor(pd[h], off);
                }
            }
            if (l15 == 0 && vr) {
                *(float4*)&as1[row * 4] = make_float4(ps[0], ps[1], ps[2], ps[3]);
                *(float4*)&ad1[row * 4] = make_float4(pd[0], pd[1], pd[2], pd[3]);
            }
        }
    }
}

// ---------------- aggregation layer 1 + MFMA-fused gemm2/alpha2 ----------------
// PERSISTENT grid-stride version: 2048 blocks loop over node-groups; W2 staged
// to LDS ONCE per block (was once per 8 nodes = 200 MB of L2 re-reads + a
// barrier bubble per 8 nodes). Per-group body identical to r7's proven kernel.

__device__ __forceinline__ void edge_fma(uint4 u0, float w, v2f* acc) {
    v2f wv = {w, w};
    v2f t;
    t.x = bflo(u0.x); t.y = bfhi(u0.x); acc[0] += wv * t;
    t.x = bflo(u0.y); t.y = bfhi(u0.y); acc[1] += wv * t;
    t.x = bflo(u0.z); t.y = bfhi(u0.z); acc[2] += wv * t;
    t.x = bflo(u0.w); t.y = bfhi(u0.w); acc[3] += wv * t;
}

__device__ __forceinline__ void accum_tbl1(int srcReg, const float* __restrict__ ew, int mcount,
                                           const uint4* __restrict__ h1v4,
                                           int lanebase, int sub, int cg, int hh, v2f* acc) {
    int b = 0;
    for (; b + 8 <= mcount; b += 8) {
        int i0 = b + sub, i1 = b + 2 + sub, i2 = b + 4 + sub, i3 = b + 6 + sub;
        int s0 = __shfl(srcReg, lanebase + i0);
        int s1 = __shfl(srcReg, lanebase + i1);
        int s2 = __shfl(srcReg, lanebase + i2);
        int s3 = __shfl(srcReg, lanebase + i3);
        float w_0 = ew[i0 * 4 + hh];
        float w_1 = ew[i1 * 4 + hh];
        float w_2 = ew[i2 * 4 + hh];
        float w_3 = ew[i3 * 4 + hh];
        uint4 u0 = h1v4[(unsigned)(s0 * 16 + cg)];
        uint4 u1 = h1v4[(unsigned)(s1 * 16 + cg)];
        uint4 u2 = h1v4[(unsigned)(s2 * 16 + cg)];
        uint4 u3 = h1v4[(unsigned)(s3 * 16 + cg)];
        edge_fma(u0, w_0, acc);
        edge_fma(u1, w_1, acc);
        edge_fma(u2, w_2, acc);
        edge_fma(u3, w_3, acc);
    }
    if (b + 4 <= mcount) {
        int i0 = b + sub, i1 = b + 2 + sub;
        int s0 = __shfl(srcReg, lanebase + i0);
        int s1 = __shfl(srcReg, lanebase + i1);
        float w_0 = ew[i0 * 4 + hh];
        float w_1 = ew[i1 * 4 + hh];
        uint4 u0 = h1v4[(unsigned)(s0 * 16 + cg)];
        uint4 u1 = h1v4[(unsigned)(s1 * 16 + cg)];
        edge_fma(u0, w_0, acc);
        edge_fma(u1, w_1, acc);
        b += 4;
    }
    if (b + 2 <= mcount) {
        int i0 = b + sub;
        int s0 = __shfl(srcReg, lanebase + i0);
        float w_0 = ew[i0 * 4 + hh];
        uint4 u0 = h1v4[(unsigned)(s0 * 16 + cg)];
        edge_fma(u0, w_0, acc);
        b += 2;
    }
    if (b < mcount) {                       // exactly one edge left
        int s0 = __shfl(srcReg, lanebase + b);   // uniform index per half-wave
        if (sub == 0) {
            float w_0 = ew[b * 4 + hh];
            uint4 u0 = h1v4[(unsigned)(s0 * 16 + cg)];
            edge_fma(u0, w_0, acc);
        }
    }
}

__global__ void __launch_bounds__(256)
agg1_kernel(const int* __restrict__ csr, const int* __restrict__ indptr,
            const int* __restrict__ counts, const float* __restrict__ as1,
            const float* __restrict__ ad1, const unsigned short* __restrict__ h1b,
            const float* __restrict__ b1, const unsigned short* __restrict__ w2p,
            const float* __restrict__ a_s2, const float* __restrict__ a_d2,
            unsigned short* __restrict__ h2b, float* __restrict__ as2,
            float* __restrict__ ad2, int N, int ngroups) {
    __shared__ __attribute__((aligned(16))) float ewt[4][2][128];  // ew tables / xa  4 KB
    __shared__ __attribute__((aligned(16))) unsigned short w2s[8192]; // W2 B-frags  16 KB
    int tid = threadIdx.x;
    // block-wide W2 staging ONCE
    {
        const uint4* w4 = (const uint4*)w2p;
        uint4* s4 = (uint4*)w2s;
        for (int i = tid; i < 1024; i += 256) s4[i] = w4[i];
    }
    __syncthreads();

    int lane = tid & 63;
    int wv = tid >> 6;
    int l32 = lane & 31;
    int lanebase = lane & 32;
    float* ew = ewt[wv][lane >> 5];
    unsigned short* xa = (unsigned short*)&ewt[wv][0][0];
    int sub = l32 >> 4;       // edge subgroup within the 32-lane node group
    int cg = lane & 15;       // channel group (8 ch each)
    int hh = cg >> 2;         // head
    int rowA = lane & 15;
    int kb = lane >> 4;
    const uint4* h1v4 = (const uint4*)h1b;

    for (int g = blockIdx.x; g < ngroups; g += gridDim.x) {
        int n = g * 8 + wv * 2 + (lane >> 5);
        bool valid = (n < N);               // full wave stays active (MFMA needs 64 lanes)
        int nsafe = valid ? n : 0;
        int start = indptr[nsafe];
        int cnt = valid ? counts[nsafe] : 0;
        float4 ad4 = ((const float4*)ad1)[nsafe];

        // lane i <-> edge i within the 32-lane group; no max pass (exp safe in fp32)
        int src0 = 0;
        float4 p0 = make_float4(0.f, 0.f, 0.f, 0.f);
        if (l32 < cnt) {
            src0 = csr[start + l32];
            float4 a = ((const float4*)as1)[src0];
            p0.x = __expf(leaky(a.x + ad4.x));
            p0.y = __expf(leaky(a.y + ad4.y));
            p0.z = __expf(leaky(a.z + ad4.z));
            p0.w = __expf(leaky(a.w + ad4.w));
        }
        float4 l4 = p0;
        if (cnt > 32) {                         // rare (~3e-4 of nodes)
            for (int base = 32; base < cnt; base += 32) {
                if (base + l32 < cnt) {
                    int s = csr[start + base + l32];
                    float4 a = ((const float4*)as1)[s];
                    l4.x += __expf(leaky(a.x + ad4.x));
                    l4.y += __expf(leaky(a.y + ad4.y));
                    l4.z += __expf(leaky(a.z + ad4.z));
                    l4.w += __expf(leaky(a.w + ad4.w));
                }
            }
        }
#pragma unroll
        for (int off = 16; off >= 1; off >>= 1) {   // xor<32 stays within the 32-group
            l4.x += __shfl_xor(l4.x, off);
            l4.y += __shfl_xor(l4.y, off);
            l4.z += __shfl_xor(l4.z, off);
            l4.w += __shfl_xor(l4.w, off);
        }
        float4 li = make_float4(1.f / l4.x, 1.f / l4.y, 1.f / l4.z, 1.f / l4.w);
        float4 w0 = make_float4(p0.x * li.x, p0.y * li.y, p0.z * li.z, p0.w * li.w);

        // weight table to LDS (same-wave write/read: no barrier needed)
        *(float4*)&ew[l32 * 4] = w0;

        v2f acc[4];
        acc[0] = acc[1] = acc[2] = acc[3] = (v2f){0.f, 0.f};
        accum_tbl1(src0, ew, min(cnt, 32), h1v4, lanebase, sub, cg, hh, acc);
        if (cnt > 32) {
            for (int base = 32; base < cnt; base += 32) {
                int srcc = 0;
                float4 wc = make_float4(0.f, 0.f, 0.f, 0.f);
                if (base + l32 < cnt) {
                    srcc = csr[start + base + l32];
                    float4 a = ((const float4*)as1)[srcc];
                    wc.x = __expf(leaky(a.x + ad4.x)) * li.x;
                    wc.y = __expf(leaky(a.y + ad4.y)) * li.y;
                    wc.z = __expf(leaky(a.z + ad4.z)) * li.z;
                    wc.w = __expf(leaky(a.w + ad4.w)) * li.w;
                }
                *(float4*)&ew[l32 * 4] = wc;   // overwrite table (intra-wave ordered)
                accum_tbl1(srcc, ew, min(cnt - base, 32), h1v4, lanebase, sub, cg, hh, acc);
            }
        }
        // merge the 2 sub-group partials (within the 32-lane group)
#pragma unroll
        for (int i = 0; i < 4; i++) {
            acc[i].x += __shfl_xor(acc[i].x, 16);
            acc[i].y += __shfl_xor(acc[i].y, 16);
        }
        // x1 row (bias + ELU) -> bf16 A-fragment staging area (ewt[wv] is dead now).
        if (l32 < 16) {
            const float4* b4 = (const float4*)b1;
            float4 ba = b4[cg * 2], bb = b4[cg * 2 + 1];
            float o[8];
            o[0] = acc[0].x + ba.x; o[1] = acc[0].y + ba.y;
            o[2] = acc[1].x + ba.z; o[3] = acc[1].y + ba.w;
            o[4] = acc[2].x + bb.x; o[5] = acc[2].y + bb.y;
            o[6] = acc[3].x + bb.z; o[7] = acc[3].y + bb.w;
#pragma unroll
            for (int j = 0; j < 8; j++) o[j] = (o[j] > 0.f) ? o[j] : (__expf(o[j]) - 1.f);  // ELU
            uint4 pk;
            pk.x = (unsigned)f2bf(o[0]) | ((unsigned)f2bf(o[1]) << 16);
            pk.y = (unsigned)f2bf(o[2]) | ((unsigned)f2bf(o[3]) << 16);
            pk.z = (unsigned)f2bf(o[4]) | ((unsigned)f2bf(o[5]) << 16);
            pk.w = (unsigned)f2bf(o[6]) | ((unsigned)f2bf(o[7]) << 16);
            *(uint4*)&xa[cg * 16 + (lane >> 5) * 8] = pk;
        }
        // MFMA gemm2: D(16x16 per col-tile) rows 0/1 = this wave's 2 nodes.
        f32x4 hacc[4];
#pragma unroll
        for (int c = 0; c < 4; c++) hacc[c] = (f32x4){0.f, 0.f, 0.f, 0.f};
#pragma unroll
        for (int t = 0; t < 4; t++) {
            bf16x8 af = {0, 0, 0, 0, 0, 0, 0, 0};
            if (rowA < 2) af = *(const bf16x8*)&xa[(t * 4 + kb) * 16 + rowA * 8];
#pragma unroll
            for (int c = 0; c < 4; c++) {
                bf16x8 bf = *(const bf16x8*)&w2s[((t * 4 + c) * 64 + lane) * 8];
                hacc[c] = __builtin_amdgcn_mfma_f32_16x16x32_bf16(af, bf, hacc[c], 0, 0, 0);
            }
        }
        // epilogue: h2 bf16 + alpha2 dots (C layout: col=lane&15, row=(lane>>4)*4+reg)
        int na = g * 8 + wv * 2;
        int nb = na + 1;
        bool va = (na < N), vb = (nb < N);
        if (lane < 16) {
            float psa = 0.f, pda = 0.f, psb = 0.f, pdb = 0.f;
#pragma unroll
            for (int c = 0; c < 4; c++) {
                float h0 = hacc[c][0];     // row 0 = node a
                float h1r = hacc[c][1];    // row 1 = node b
                float asv = a_s2[c * 16 + lane];
                float adv = a_d2[c * 16 + lane];
                psa = fmaf(h0, asv, psa); pda = fmaf(h0, adv, pda);
                psb = fmaf(h1r, asv, psb); pdb = fmaf(h1r, adv, pdb);
                if (va) h2b[(size_t)na * 64 + c * 16 + lane] = f2bf(h0);
                if (vb) h2b[(size_t)nb * 64 + c * 16 + lane] = f2bf(h1r);
            }
#pragma unroll
            for (int off = 8; off >= 1; off >>= 1) {
                psa += __shfl_xor(psa, off); pda += __shfl_xor(pda, off);
                psb += __shfl_xor(psb, off); pdb += __shfl_xor(pdb, off);
            }
            if (lane == 0) {
                if (va) { as2[na] = psa; ad2[na] = pda; }
                if (vb) { as2[nb] = psb; ad2[nb] = pdb; }
            }
        }
    }
}

// ---------------- aggregation layer 2: 32 lanes/node, 8 lanes/edge, grid-stride ----------------

__device__ __forceinline__ void accum2(int srcReg, float wReg, int mcount,
                                       const uint4* __restrict__ h2v4,
                                       int lanebase, int sub, int cg, v2f* acc) {
    int b = 0;
    for (; b + 16 <= mcount; b += 16) {
        int i0 = b + sub, i1 = b + 4 + sub, i2 = b + 8 + sub, i3 = b + 12 + sub;
        int s0 = __shfl(srcReg, lanebase + i0);
        int s1 = __shfl(srcReg, lanebase + i1);
        int s2 = __shfl(srcReg, lanebase + i2);
        int s3 = __shfl(srcReg, lanebase + i3);
        float w_0 = __shfl(wReg, lanebase + i0);
        float w_1 = __shfl(wReg, lanebase + i1);
        float w_2 = __shfl(wReg, lanebase + i2);
        float w_3 = __shfl(wReg, lanebase + i3);
        uint4 u0 = h2v4[(unsigned)(s0 * 8 + cg)];
        uint4 u1 = h2v4[(unsigned)(s1 * 8 + cg)];
        uint4 u2 = h2v4[(unsigned)(s2 * 8 + cg)];
        uint4 u3 = h2v4[(unsigned)(s3 * 8 + cg)];
        edge_fma(u0, w_0, acc);
        edge_fma(u1, w_1, acc);
        edge_fma(u2, w_2, acc);
        edge_fma(u3, w_3, acc);
    }
    if (b + 8 <= mcount) {
        int i0 = b + sub, i1 = b + 4 + sub;
        int s0 = __shfl(srcReg, lanebase + i0);
        int s1 = __shfl(srcReg, lanebase + i1);
        float w_0 = __shfl(wReg, lanebase + i0);
        float w_1 = __shfl(wReg, lanebase + i1);
        uint4 u0 = h2v4[(unsigned)(s0 * 8 + cg)];
        uint4 u1 = h2v4[(unsigned)(s1 * 8 + cg)];
        edge_fma(u0, w_0, acc);
        edge_fma(u1, w_1, acc);
        b += 8;
    }
    if (b + 4 <= mcount) {
        int i0 = b + sub;
        int s0 = __shfl(srcReg, lanebase + i0);
        float w_0 = __shfl(wReg, lanebase + i0);
        uint4 u0 = h2v4[(unsigned)(s0 * 8 + cg)];
        edge_fma(u0, w_0, acc);
        b += 4;
    }
    if (b < mcount) {
        int rem = mcount - b;              // 1..3
        int i0 = b + sub;
        int ic = min(i0, mcount - 1);
        int s0 = __shfl(srcReg, lanebase + ic);   // all lanes active at the shfl
        float w_0 = __shfl(wReg, lanebase + ic);
        if (sub < rem) {
            uint4 u0 = h2v4[(unsigned)(s0 * 8 + cg)];
            edge_fma(u0, w_0, acc);
        }
    }
}

__global__ void __launch_bounds__(256)
agg2_kernel(const int* __restrict__ csr, const int* __restrict__ indptr,
            const int* __restrict__ counts, const float* __restrict__ as2,
            const float* __restrict__ ad2, const unsigned short* __restrict__ h2b,
            const float* __restrict__ b2, float* __restrict__ out, int N, int ngroups) {
    int lane = threadIdx.x & 63;
    int l32 = lane & 31;
    int lanebase = lane & 32;
    int sub = l32 >> 3;    // edge within 4-group
    int cg = lane & 7;     // channel group (8 ch each)
    const uint4* h2v4 = (const uint4*)h2b;

    for (int g = blockIdx.x; g < ngroups; g += gridDim.x) {
        int n = g * 8 + (threadIdx.x >> 6) * 2 + (lane >> 5);
        if (n >= N) continue;
        int start = indptr[n];
        int cnt = counts[n];
        float ad = ad2[n];

        int src0 = 0;
        float p0 = 0.f;
        if (l32 < cnt) {
            src0 = csr[start + l32];
            p0 = __expf(leaky(as2[src0] + ad));   // no max pass
        }
        float l = p0;
        if (cnt > 32) {
            for (int base = 32; base < cnt; base += 32) {
                if (base + l32 < cnt)
                    l += __expf(leaky(as2[csr[start + base + l32]] + ad));
            }
        }
#pragma unroll
        for (int off = 16; off >= 1; off >>= 1) l += __shfl_xor(l, off);
        float li = 1.f / l;
        float w0 = p0 * li;

        v2f acc[4];
        acc[0] = acc[1] = acc[2] = acc[3] = (v2f){0.f, 0.f};
        accum2(src0, w0, min(cnt, 32), h2v4, lanebase, sub, cg, acc);
        if (cnt > 32) {
            for (int base = 32; base < cnt; base += 32) {
                int srcc = 0;
                float wc = 0.f;
                if (base + l32 < cnt) {
                    srcc = csr[start + base + l32];
                    wc = __expf(leaky(as2[srcc] + ad)) * li;
                }
                accum2(srcc, wc, min(cnt - base, 32), h2v4, lanebase, sub, cg, acc);
            }
        }
#pragma unroll
        for (int i = 0; i < 4; i++) {
            acc[i].x += __shfl_xor(acc[i].x, 8);
            acc[i].x += __shfl_xor(acc[i].x, 16);
            acc[i].y += __shfl_xor(acc[i].y, 8);
            acc[i].y += __shfl_xor(acc[i].y, 16);
        }
        if (l32 < 8) {
            const float4* b4 = (const float4*)b2;
            float4 ba = b4[cg * 2], bb = b4[cg * 2 + 1];
            float4 o0, o1;
            o0.x = acc[0].x + ba.x; o0.y = acc[0].y + ba.y;
            o0.z = acc[1].x + ba.z; o0.w = acc[1].y + ba.w;
            o1.x = acc[2].x + bb.x; o1.y = acc[2].y + bb.y;
            o1.z = acc[3].x + bb.z; o1.w = acc[3].y + bb.w;
            float4* orow = (float4*)&out[(size_t)n * 64 + cg * 8];
            orow[0] = o0;
            orow[1] = o1;
        }
    }
}

// ---------------- launcher ----------------

extern "C" void kernel_launch(void* const* d_in, const int* in_sizes, int n_in,
                              void* d_out, int out_size, void* d_ws, size_t ws_size,
                              hipStream_t stream) {
    const int*   xidx = (const int*)d_in[0];
    const int*   ei   = (const int*)d_in[1];
    const float* emb  = (const float*)d_in[2];
    const float* W1   = (const float*)d_in[3];
    const float* a_s1 = (const float*)d_in[4];
    const float* a_d1 = (const float*)d_in[5];
    const float* b1   = (const float*)d_in[6];
    const float* W2   = (const float*)d_in[7];
    const float* a_s2 = (const float*)d_in[8];
    const float* a_d2 = (const float*)d_in[9];
    const float* b2   = (const float*)d_in[10];
    float* out = (float*)d_out;

    const int N  = in_sizes[0];
    const int E  = in_sizes[1] / 2;
    const int E2 = E + N;
    const int K  = (N + 255) >> BK_SHIFT;   // 391 buckets for N=100000

    // workspace layout
    int* ws_i    = (int*)d_ws;
    int* counts  = ws_i;                       // N
    int* indptr  = ws_i + N;                   // N
    int* bcounts = ws_i + 2 * (size_t)N;       // 512
    int* bbase   = ws_i + 2 * (size_t)N + 512; // 513
    int* bcursor = ws_i + 2 * (size_t)N + 1032;// 512
    int* csr     = ws_i + 2 * (size_t)N + 1544;// E2
    size_t fbase = ((size_t)(2 * (size_t)N + 1544 + E2) + 3) & ~(size_t)3;
    float* ws_f = (float*)d_ws;
    unsigned short* h1b = (unsigned short*)(ws_f + fbase);   // N*128 bf16 (N*64 floats)
    float* region2 = ws_f + fbase + (size_t)N * 64;          // old-x1b region (N*64 floats)
    unsigned short* h2b = (unsigned short*)region2;          // N*64 bf16 (N*32 floats)
    float* as2 = region2 + (size_t)N * 32;                   // N floats
    float* ad2 = region2 + (size_t)N * 33;                   // N floats
    unsigned short* w2p  = (unsigned short*)(region2 + (size_t)N * 34);          // 8192 ushorts (16KB)
    unsigned short* w1ph = (unsigned short*)(region2 + (size_t)N * 34 + 4096);   // 16384 ushorts (32KB)
    unsigned short* w1pl = (unsigned short*)(region2 + (size_t)N * 34 + 12288);  // 16384 ushorts (32KB)
    float* as1 = ws_f + fbase + (size_t)N * 128;             // N*4
    float* ad1 = as1 + (size_t)N * 4;                        // N*4
    unsigned int* bedges = (unsigned int*)region2;  // alias: dead after bcsr, before agg1 writes

    // prep: W1 hi/lo + W2 B-frag packs + bcounts zero (one dispatch)
    prep_kernel<<<(16384 + 8192 + 512 + 255) / 256, 256, 0, stream>>>(W1, W2, w1ph, w1pl, w2p, bcounts);

    // CSR build: dst-radix partition
    int nchunks = (E2 + 4095) / 4096;
    bcount_kernel<<<nchunks, 256, 0, stream>>>(ei, E, E2, K, bcounts);
    bscan_kernel<<<1, 512, 0, stream>>>(bcounts, K, bbase, bcursor);
    bscatter_kernel<<<nchunks, 256, 0, stream>>>(ei, E, E2, K, bcursor, bedges);
    bcsr_kernel<<<K, 256, 0, stream>>>(bedges, bbase, N, counts, indptr, csr);

    // Layer 1 GEMM on MFMA (bf16x3, fuses alpha1 + bf16 h1)
    gemm1_kernel<<<(N + 127) / 128, 256, 0, stream>>>(emb, xidx, w1ph, w1pl, h1b,
                                                      a_s1, a_d1, as1, ad1, N);

    // agg1 + MFMA-fused gemm2/alpha2 — persistent grid-stride (W2 staged once/block)
    int ngroups = (N + 7) / 8;
    int g1 = min(ngroups, 2048);
    agg1_kernel<<<g1, 256, 0, stream>>>(csr, indptr, counts, as1, ad1, h1b, b1,
                                        w2p, a_s2, a_d2, h2b, as2, ad2, N, ngroups);

    // Layer 2 aggregation — grid-stride
    int g2 = min(ngroups, 2048);
    agg2_kernel<<<g2, 256, 0, stream>>>(csr, indptr, counts, as2, ad2, h2b, b2, out, N, ngroups);
}

// Round 10
// 348.964 us; speedup vs baseline: 1.0704x; 1.0704x over previous
//
#include <hip/hip_runtime.h>
#include <math.h>

// GATNet: N=100000 nodes, D=128, HEADS=4, HID=32, OUT_C=64, E=1.6M (+N self-loops)
#define NEG_SLOPE 0.2f
#define BK_SHIFT 8          // bucket = dst >> 8 (256 dsts per bucket)

typedef __attribute__((ext_vector_type(2))) float v2f;
typedef __attribute__((ext_vector_type(8))) short bf16x8;   // 8 bf16 = 4 VGPRs
typedef __attribute__((ext_vector_type(4))) float f32x4;

__device__ __forceinline__ float leaky(float x) { return x > 0.f ? x : NEG_SLOPE * x; }
// fp32 -> bf16 round-to-nearest-even
__device__ __forceinline__ unsigned short f2bf(float f) {
    unsigned int x = __float_as_uint(f);
    unsigned int r = (x + 0x7fffu + ((x >> 16) & 1u)) >> 16;
    return (unsigned short)r;
}
__device__ __forceinline__ float bflo(unsigned int u) { return __uint_as_float(u << 16); }
__device__ __forceinline__ float bfhi(unsigned int u) { return __uint_as_float(u & 0xffff0000u); }

// ---------------- prep: W1 hi/lo + W2 B-fragment packs, bcounts zero ----------------

__global__ void __launch_bounds__(256) prep_kernel(const float* __restrict__ W1,
                                                   const float* __restrict__ W2,
                                                   unsigned short* __restrict__ w1ph,
                                                   unsigned short* __restrict__ w1pl,
                                                   unsigned short* __restrict__ w2p,
                                                   int* __restrict__ bcounts) {
    int i = blockIdx.x * 256 + threadIdx.x;
    if (i < 16384) {
        int j = i & 7, l = (i >> 3) & 63, c = (i >> 9) & 7, t = i >> 12;
        int k = t * 32 + ((l >> 4) << 3) + j;
        int col = c * 16 + (l & 15);
        float v = W1[k * 128 + col];
        unsigned short hi = f2bf(v);
        w1ph[i] = hi;
        w1pl[i] = f2bf(v - __uint_as_float((unsigned)hi << 16));
    } else if (i < 16384 + 8192) {
        int i2 = i - 16384;
        int t = i2 >> 11, c = (i2 >> 9) & 3, l = (i2 >> 3) & 63, j = i2 & 7;
        int k = t * 32 + (l >> 4) * 8 + j;
        int col = c * 16 + (l & 15);
        w2p[i2] = f2bf(W2[k * 64 + col]);
    } else if (i < 16384 + 8192 + 512) {
        bcounts[i - 16384 - 8192] = 0;
    }
}

// ---------------- CSR build: dst-radix partition ----------------

__global__ void __launch_bounds__(256) bcount_kernel(const int* __restrict__ ei, int E, int E2,
                                                     int K, int* __restrict__ bcounts) {
    __shared__ int h[512];
    int t = threadIdx.x;
    h[t] = 0; h[t + 256] = 0;
    __syncthreads();
    int base = blockIdx.x * 4096;
#pragma unroll 4
    for (int i = 0; i < 16; i++) {
        int e = base + i * 256 + t;
        if (e < E2) {
            int dst = (e < E) ? ei[E + e] : (e - E);
            atomicAdd(&h[dst >> BK_SHIFT], 1);
        }
    }
    __syncthreads();
    for (int b = t; b < K; b += 256) {
        int c = h[b];
        if (c) atomicAdd(&bcounts[b], c);
    }
}

__global__ void __launch_bounds__(512) bscan_kernel(const int* __restrict__ bcounts, int K,
                                                    int* __restrict__ bbase, int* __restrict__ bcursor) {
    __shared__ int s[512];
    int t = threadIdx.x;
    int v = (t < K) ? bcounts[t] : 0;
    s[t] = v;
    __syncthreads();
    for (int off = 1; off < 512; off <<= 1) {
        int u = (t >= off) ? s[t - off] : 0;
        __syncthreads();
        s[t] += u;
        __syncthreads();
    }
    if (t < K) {
        int ex = s[t] - v;
        bbase[t] = ex;
        bcursor[t] = ex;
    }
    if (t == 511) bbase[K] = s[511];
}

// stage packed (src<<8 | dstLow8) + u16 bin tag; copy out in coalesced runs
__global__ void __launch_bounds__(256) bscatter_kernel(const int* __restrict__ ei, int E, int E2,
                                                       int K, int* __restrict__ bcursor,
                                                       unsigned int* __restrict__ bedges) {
    __shared__ int hist[512], pre[512], lcur[512], gbase[512], psum[256];
    __shared__ unsigned int stage[4096];
    __shared__ unsigned short binof[4096];
    int t = threadIdx.x;
    hist[t] = 0; hist[t + 256] = 0;
    __syncthreads();
    int base = blockIdx.x * 4096;
    int cnt = min(4096, E2 - base);
    int s_[16], d_[16];
#pragma unroll
    for (int i = 0; i < 16; i++) {
        int e = base + i * 256 + t;
        if (e < E2) {
            int ss, dd;
            if (e < E) { ss = ei[e]; dd = ei[E + e]; }
            else       { ss = e - E; dd = ss; }
            s_[i] = ss; d_[i] = dd;
            atomicAdd(&hist[dd >> BK_SHIFT], 1);
        }
    }
    __syncthreads();
    int a0 = hist[2 * t], a1 = hist[2 * t + 1];
    psum[t] = a0 + a1;
    __syncthreads();
    for (int off = 1; off < 256; off <<= 1) {
        int u = (t >= off) ? psum[t - off] : 0;
        __syncthreads();
        psum[t] += u;
        __syncthreads();
    }
    int pex = psum[t] - (a0 + a1);
    pre[2 * t] = pex;
    pre[2 * t + 1] = pex + a0;
    __syncthreads();
    for (int b = t; b < K; b += 256) {
        int c = hist[b];
        if (c) gbase[b] = atomicAdd(&bcursor[b], c);
    }
    lcur[t] = pre[t]; lcur[t + 256] = pre[t + 256];
    __syncthreads();
#pragma unroll
    for (int i = 0; i < 16; i++) {
        int e = base + i * 256 + t;
        if (e < E2) {
            int bin = d_[i] >> BK_SHIFT;
            int p = atomicAdd(&lcur[bin], 1);
            stage[p] = ((unsigned)s_[i] << 8) | (unsigned)(d_[i] & 255);
            binof[p] = (unsigned short)bin;
        }
    }
    __syncthreads();
    for (int i = t; i < cnt; i += 256) {
        unsigned int ed = stage[i];
        int bin = (int)binof[i];
        bedges[gbase[bin] + (i - pre[bin])] = ed;
    }
}

__global__ void __launch_bounds__(256) bcsr_kernel(const unsigned int* __restrict__ bedges,
                                                   const int* __restrict__ bbase, int N,
                                                   int* __restrict__ counts, int* __restrict__ indptr,
                                                   int* __restrict__ csr) {
    __shared__ int hist[256], scn[256], cur[256];
    int b = blockIdx.x;
    int t = threadIdx.x;
    int base = bbase[b];
    int cnt = bbase[b + 1] - base;
    hist[t] = 0;
    __syncthreads();
    for (int i = t; i < cnt; i += 256) {
        atomicAdd(&hist[bedges[base + i] & 255u], 1);
    }
    __syncthreads();
    int v = hist[t];
    scn[t] = v;
    __syncthreads();
    for (int off = 1; off < 256; off <<= 1) {
        int u = (t >= off) ? scn[t - off] : 0;
        __syncthreads();
        scn[t] += u;
        __syncthreads();
    }
    int ex = scn[t] - v;
    int d = (b << BK_SHIFT) + t;
    if (d < N) { counts[d] = v; indptr[d] = base + ex; }
    cur[t] = ex;
    __syncthreads();
    for (int i = t; i < cnt; i += 256) {
        unsigned int ed = bedges[base + i];
        int p = atomicAdd(&cur[ed & 255u], 1);
        csr[base + p] = (int)(ed >> 8);
    }
}

// ---------------- gemm1 on MFMA: bf16x3 split (near-fp32), fused alpha1 ----------------

__global__ __launch_bounds__(256) void gemm1_kernel(const float* __restrict__ emb,
                             const int* __restrict__ xidx,
                             const unsigned short* __restrict__ w1ph,
                             const unsigned short* __restrict__ w1pl,
                             unsigned short* __restrict__ h1b,
                             const float* __restrict__ a_s1, const float* __restrict__ a_d1,
                             float* __restrict__ as1, float* __restrict__ ad1, int N) {
    __shared__ __attribute__((aligned(16))) unsigned short w1s[2][16384];   // 64 KB
    int tid = threadIdx.x;
    {
        const uint4* h4 = (const uint4*)w1ph;
        const uint4* l4 = (const uint4*)w1pl;
        uint4* sh = (uint4*)w1s[0];
        uint4* sl = (uint4*)w1s[1];
        for (int i = tid; i < 2048; i += 256) { sh[i] = h4[i]; sl[i] = l4[i]; }
    }
    __syncthreads();
    int lane = tid & 63;
    int wv = tid >> 6;
    int l15 = lane & 15;
    int kb = lane >> 4;
    int r0 = blockIdx.x * 128 + wv * 32;
    int sA[2];
#pragma unroll
    for (int rt = 0; rt < 2; rt++) {
        int r = r0 + rt * 16 + l15;
        sA[rt] = xidx[min(r, N - 1)];
    }
    f32x4 acc[2][8];
#pragma unroll
    for (int rt = 0; rt < 2; rt++)
#pragma unroll
        for (int c = 0; c < 8; c++) acc[rt][c] = (f32x4){0.f, 0.f, 0.f, 0.f};

#pragma unroll
    for (int t = 0; t < 4; t++) {
        bf16x8 ahi[2], alo[2];
#pragma unroll
        for (int rt = 0; rt < 2; rt++) {
            const float* ap = emb + (size_t)sA[rt] * 128 + t * 32 + kb * 8;
            float4 a0 = *(const float4*)ap;
            float4 a1 = *(const float4*)(ap + 4);
            float av[8] = {a0.x, a0.y, a0.z, a0.w, a1.x, a1.y, a1.z, a1.w};
#pragma unroll
            for (int j = 0; j < 8; j++) {
                unsigned short hi = f2bf(av[j]);
                ahi[rt][j] = (short)hi;
                alo[rt][j] = (short)f2bf(av[j] - __uint_as_float((unsigned)hi << 16));
            }
        }
#pragma unroll
        for (int c = 0; c < 8; c++) {
            bf16x8 bhi = *(const bf16x8*)&w1s[0][((t * 8 + c) * 64 + lane) * 8];
            bf16x8 blo = *(const bf16x8*)&w1s[1][((t * 8 + c) * 64 + lane) * 8];
#pragma unroll
            for (int rt = 0; rt < 2; rt++) {
                acc[rt][c] = __builtin_amdgcn_mfma_f32_16x16x32_bf16(ahi[rt], bhi, acc[rt][c], 0, 0, 0);
                acc[rt][c] = __builtin_amdgcn_mfma_f32_16x16x32_bf16(alo[rt], bhi, acc[rt][c], 0, 0, 0);
                acc[rt][c] = __builtin_amdgcn_mfma_f32_16x16x32_bf16(ahi[rt], blo, acc[rt][c], 0, 0, 0);
            }
        }
    }
    // epilogue: h1 bf16 stores + alpha dots from C-regs
    float asv[8], adv[8];
#pragma unroll
    for (int c = 0; c < 8; c++) {
        asv[c] = a_s1[c * 16 + l15];     // flat [head*32+hid] == col index
        adv[c] = a_d1[c * 16 + l15];
    }
#pragma unroll
    for (int rt = 0; rt < 2; rt++) {
#pragma unroll
        for (int reg = 0; reg < 4; reg++) {
            int row = r0 + rt * 16 + kb * 4 + reg;
            bool vr = row < N;
            if (vr) {
#pragma unroll
                for (int c = 0; c < 8; c++)
                    h1b[(size_t)row * 128 + c * 16 + l15] = f2bf(acc[rt][c][reg]);
            }
            float ps[4], pd[4];
#pragma unroll
            for (int h = 0; h < 4; h++) {
                ps[h] = acc[rt][2 * h][reg] * asv[2 * h] + acc[rt][2 * h + 1][reg] * asv[2 * h + 1];
                pd[h] = acc[rt][2 * h][reg] * adv[2 * h] + acc[rt][2 * h + 1][reg] * adv[2 * h + 1];
            }
#pragma unroll
            for (int off = 1; off <= 8; off <<= 1) {
#pragma unroll
                for (int h = 0; h < 4; h++) {
                    ps[h] += __shfl_xor(ps[h], off);
                    pd[h] += __shfl_xor(pd[h], off);
                }
            }
            if (l15 == 0 && vr) {
                *(float4*)&as1[row * 4] = make_float4(ps[0], ps[1], ps[2], ps[3]);
                *(float4*)&ad1[row * 4] = make_float4(pd[0], pd[1], pd[2], pd[3]);
            }
        }
    }
}

// ---------------- aggregation layer 1 + MFMA-fused gemm2/alpha2 ----------------
// r8 single-shot structure (no loop-carried state -> VGPR ~48), but 512-thread
// blocks: 16 nodes/block, so the 16 KB W2 staging + startup barrier are paid
// half as often as r8 (6250 blocks vs 12500). LDS = 8 KB ewt + 16 KB w2s = 24 KB
// -> thread-capped 4 blocks/CU x 8 waves = full occupancy if VGPR <= 64.

__device__ __forceinline__ void edge_fma(uint4 u0, float w, v2f* acc) {
    v2f wv = {w, w};
    v2f t;
    t.x = bflo(u0.x); t.y = bfhi(u0.x); acc[0] += wv * t;
    t.x = bflo(u0.y); t.y = bfhi(u0.y); acc[1] += wv * t;
    t.x = bflo(u0.z); t.y = bfhi(u0.z); acc[2] += wv * t;
    t.x = bflo(u0.w); t.y = bfhi(u0.w); acc[3] += wv * t;
}

__device__ __forceinline__ void accum_tbl1(int srcReg, const float* __restrict__ ew, int mcount,
                                           const uint4* __restrict__ h1v4,
                                           int lanebase, int sub, int cg, int hh, v2f* acc) {
    int b = 0;
    for (; b + 8 <= mcount; b += 8) {
        int i0 = b + sub, i1 = b + 2 + sub, i2 = b + 4 + sub, i3 = b + 6 + sub;
        int s0 = __shfl(srcReg, lanebase + i0);
        int s1 = __shfl(srcReg, lanebase + i1);
        int s2 = __shfl(srcReg, lanebase + i2);
        int s3 = __shfl(srcReg, lanebase + i3);
        float w_0 = ew[i0 * 4 + hh];
        float w_1 = ew[i1 * 4 + hh];
        float w_2 = ew[i2 * 4 + hh];
        float w_3 = ew[i3 * 4 + hh];
        uint4 u0 = h1v4[(unsigned)(s0 * 16 + cg)];
        uint4 u1 = h1v4[(unsigned)(s1 * 16 + cg)];
        uint4 u2 = h1v4[(unsigned)(s2 * 16 + cg)];
        uint4 u3 = h1v4[(unsigned)(s3 * 16 + cg)];
        edge_fma(u0, w_0, acc);
        edge_fma(u1, w_1, acc);
        edge_fma(u2, w_2, acc);
        edge_fma(u3, w_3, acc);
    }
    if (b + 4 <= mcount) {
        int i0 = b + sub, i1 = b + 2 + sub;
        int s0 = __shfl(srcReg, lanebase + i0);
        int s1 = __shfl(srcReg, lanebase + i1);
        float w_0 = ew[i0 * 4 + hh];
        float w_1 = ew[i1 * 4 + hh];
        uint4 u0 = h1v4[(unsigned)(s0 * 16 + cg)];
        uint4 u1 = h1v4[(unsigned)(s1 * 16 + cg)];
        edge_fma(u0, w_0, acc);
        edge_fma(u1, w_1, acc);
        b += 4;
    }
    if (b + 2 <= mcount) {
        int i0 = b + sub;
        int s0 = __shfl(srcReg, lanebase + i0);
        float w_0 = ew[i0 * 4 + hh];
        uint4 u0 = h1v4[(unsigned)(s0 * 16 + cg)];
        edge_fma(u0, w_0, acc);
        b += 2;
    }
    if (b < mcount) {                       // exactly one edge left
        int s0 = __shfl(srcReg, lanebase + b);   // uniform index per half-wave
        if (sub == 0) {
            float w_0 = ew[b * 4 + hh];
            uint4 u0 = h1v4[(unsigned)(s0 * 16 + cg)];
            edge_fma(u0, w_0, acc);
        }
    }
}

__global__ void __launch_bounds__(512, 8)
agg1_kernel(const int* __restrict__ csr, const int* __restrict__ indptr,
            const int* __restrict__ counts, const float* __restrict__ as1,
            const float* __restrict__ ad1, const unsigned short* __restrict__ h1b,
            const float* __restrict__ b1, const unsigned short* __restrict__ w2p,
            const float* __restrict__ a_s2, const float* __restrict__ a_d2,
            unsigned short* __restrict__ h2b, float* __restrict__ as2,
            float* __restrict__ ad2, int N) {
    __shared__ __attribute__((aligned(16))) float ewt[8][2][128];  // ew tables / xa  8 KB
    __shared__ __attribute__((aligned(16))) unsigned short w2s[8192]; // W2 B-frags  16 KB
    int tid = threadIdx.x;
    // block-wide W2 staging BEFORE any divergence/return
    {
        const uint4* w4 = (const uint4*)w2p;
        uint4* s4 = (uint4*)w2s;
        for (int i = tid; i < 1024; i += 512) s4[i] = w4[i];
    }
    __syncthreads();

    int lane = tid & 63;
    int wv = tid >> 6;                      // 0..7
    int l32 = lane & 31;
    int lanebase = lane & 32;
    int n = blockIdx.x * 16 + wv * 2 + (lane >> 5);
    bool valid = (n < N);               // full wave stays active (MFMA needs 64 lanes)
    int nsafe = valid ? n : 0;
    int start = indptr[nsafe];
    int cnt = valid ? counts[nsafe] : 0;
    float4 ad4 = ((const float4*)ad1)[nsafe];

    // lane i <-> edge i within the 32-lane group; no max pass (exp safe in fp32)
    int src0 = 0;
    float4 p0 = make_float4(0.f, 0.f, 0.f, 0.f);
    if (l32 < cnt) {
        src0 = csr[start + l32];
        float4 a = ((const float4*)as1)[src0];
        p0.x = __expf(leaky(a.x + ad4.x));
        p0.y = __expf(leaky(a.y + ad4.y));
        p0.z = __expf(leaky(a.z + ad4.z));
        p0.w = __expf(leaky(a.w + ad4.w));
    }
    float4 l4 = p0;
    if (cnt > 32) {                         // rare (~3e-4 of nodes)
        for (int base = 32; base < cnt; base += 32) {
            if (base + l32 < cnt) {
                int s = csr[start + base + l32];
                float4 a = ((const float4*)as1)[s];
                l4.x += __expf(leaky(a.x + ad4.x));
                l4.y += __expf(leaky(a.y + ad4.y));
                l4.z += __expf(leaky(a.z + ad4.z));
                l4.w += __expf(leaky(a.w + ad4.w));
            }
        }
    }
#pragma unroll
    for (int off = 16; off >= 1; off >>= 1) {   // xor<32 stays within the 32-group
        l4.x += __shfl_xor(l4.x, off);
        l4.y += __shfl_xor(l4.y, off);
        l4.z += __shfl_xor(l4.z, off);
        l4.w += __shfl_xor(l4.w, off);
    }
    float4 li = make_float4(1.f / l4.x, 1.f / l4.y, 1.f / l4.z, 1.f / l4.w);
    float4 w0 = make_float4(p0.x * li.x, p0.y * li.y, p0.z * li.z, p0.w * li.w);

    // weight table to LDS (same-wave write/read: no barrier needed)
    float* ew = ewt[wv][lane >> 5];
    *(float4*)&ew[l32 * 4] = w0;

    int sub = l32 >> 4;       // edge subgroup within the 32-lane node group
    int cg = lane & 15;       // channel group (8 ch each)
    int hh = cg >> 2;         // head
    const uint4* h1v4 = (const uint4*)h1b;
    v2f acc[4];
    acc[0] = acc[1] = acc[2] = acc[3] = (v2f){0.f, 0.f};
    accum_tbl1(src0, ew, min(cnt, 32), h1v4, lanebase, sub, cg, hh, acc);
    if (cnt > 32) {
        for (int base = 32; base < cnt; base += 32) {
            int srcc = 0;
            float4 wc = make_float4(0.f, 0.f, 0.f, 0.f);
            if (base + l32 < cnt) {
                srcc = csr[start + base + l32];
                float4 a = ((const float4*)as1)[srcc];
                wc.x = __expf(leaky(a.x + ad4.x)) * li.x;
                wc.y = __expf(leaky(a.y + ad4.y)) * li.y;
                wc.z = __expf(leaky(a.z + ad4.z)) * li.z;
                wc.w = __expf(leaky(a.w + ad4.w)) * li.w;
            }
            *(float4*)&ew[l32 * 4] = wc;   // overwrite table (intra-wave ordered)
            accum_tbl1(srcc, ew, min(cnt - base, 32), h1v4, lanebase, sub, cg, hh, acc);
        }
    }
    // merge the 2 sub-group partials (within the 32-lane group)
#pragma unroll
    for (int i = 0; i < 4; i++) {
        acc[i].x += __shfl_xor(acc[i].x, 16);
        acc[i].y += __shfl_xor(acc[i].y, 16);
    }
    // x1 row (bias + ELU) -> bf16 A-fragment staging area (ewt[wv] is dead now).
    unsigned short* xa = (unsigned short*)&ewt[wv][0][0];
    if (l32 < 16) {
        const float4* b4 = (const float4*)b1;
        float4 ba = b4[cg * 2], bb = b4[cg * 2 + 1];
        float o[8];
        o[0] = acc[0].x + ba.x; o[1] = acc[0].y + ba.y;
        o[2] = acc[1].x + ba.z; o[3] = acc[1].y + ba.w;
        o[4] = acc[2].x + bb.x; o[5] = acc[2].y + bb.y;
        o[6] = acc[3].x + bb.z; o[7] = acc[3].y + bb.w;
#pragma unroll
        for (int j = 0; j < 8; j++) o[j] = (o[j] > 0.f) ? o[j] : (__expf(o[j]) - 1.f);  // ELU
        uint4 pk;
        pk.x = (unsigned)f2bf(o[0]) | ((unsigned)f2bf(o[1]) << 16);
        pk.y = (unsigned)f2bf(o[2]) | ((unsigned)f2bf(o[3]) << 16);
        pk.z = (unsigned)f2bf(o[4]) | ((unsigned)f2bf(o[5]) << 16);
        pk.w = (unsigned)f2bf(o[6]) | ((unsigned)f2bf(o[7]) << 16);
        *(uint4*)&xa[cg * 16 + (lane >> 5) * 8] = pk;
    }
    // MFMA gemm2: D(16x16 per col-tile) rows 0/1 = this wave's 2 nodes.
    int rowA = lane & 15;
    int kb = lane >> 4;
    f32x4 hacc[4];
#pragma unroll
    for (int c = 0; c < 4; c++) hacc[c] = (f32x4){0.f, 0.f, 0.f, 0.f};
#pragma unroll
    for (int t = 0; t < 4; t++) {
        bf16x8 af = {0, 0, 0, 0, 0, 0, 0, 0};
        if (rowA < 2) af = *(const bf16x8*)&xa[(t * 4 + kb) * 16 + rowA * 8];
#pragma unroll
        for (int c = 0; c < 4; c++) {
            bf16x8 bf = *(const bf16x8*)&w2s[((t * 4 + c) * 64 + lane) * 8];
            hacc[c] = __builtin_amdgcn_mfma_f32_16x16x32_bf16(af, bf, hacc[c], 0, 0, 0);
        }
    }
    // epilogue: h2 bf16 + alpha2 dots (C layout: col=lane&15, row=(lane>>4)*4+reg)
    int na = blockIdx.x * 16 + wv * 2;
    int nb = na + 1;
    bool va = (na < N), vb = (nb < N);
    if (lane < 16) {
        float psa = 0.f, pda = 0.f, psb = 0.f, pdb = 0.f;
#pragma unroll
        for (int c = 0; c < 4; c++) {
            float h0 = hacc[c][0];     // row 0 = node a
            float h1r = hacc[c][1];    // row 1 = node b
            float asv = a_s2[c * 16 + lane];
            float adv = a_d2[c * 16 + lane];
            psa = fmaf(h0, asv, psa); pda = fmaf(h0, adv, pda);
            psb = fmaf(h1r, asv, psb); pdb = fmaf(h1r, adv, pdb);
            if (va) h2b[(size_t)na * 64 + c * 16 + lane] = f2bf(h0);
            if (vb) h2b[(size_t)nb * 64 + c * 16 + lane] = f2bf(h1r);
        }
#pragma unroll
        for (int off = 8; off >= 1; off >>= 1) {
            psa += __shfl_xor(psa, off); pda += __shfl_xor(pda, off);
            psb += __shfl_xor(psb, off); pdb += __shfl_xor(pdb, off);
        }
        if (lane == 0) {
            if (va) { as2[na] = psa; ad2[na] = pda; }
            if (vb) { as2[nb] = psb; ad2[nb] = pdb; }
        }
    }
}

// ---------------- aggregation layer 2: 32 lanes/node, 8 lanes/edge ----------------

__device__ __forceinline__ void accum2(int srcReg, float wReg, int mcount,
                                       const uint4* __restrict__ h2v4,
                                       int lanebase, int sub, int cg, v2f* acc) {
    int b = 0;
    for (; b + 16 <= mcount; b += 16) {
        int i0 = b + sub, i1 = b + 4 + sub, i2 = b + 8 + sub, i3 = b + 12 + sub;
        int s0 = __shfl(srcReg, lanebase + i0);
        int s1 = __shfl(srcReg, lanebase + i1);
        int s2 = __shfl(srcReg, lanebase + i2);
        int s3 = __shfl(srcReg, lanebase + i3);
        float w_0 = __shfl(wReg, lanebase + i0);
        float w_1 = __shfl(wReg, lanebase + i1);
        float w_2 = __shfl(wReg, lanebase + i2);
        float w_3 = __shfl(wReg, lanebase + i3);
        uint4 u0 = h2v4[(unsigned)(s0 * 8 + cg)];
        uint4 u1 = h2v4[(unsigned)(s1 * 8 + cg)];
        uint4 u2 = h2v4[(unsigned)(s2 * 8 + cg)];
        uint4 u3 = h2v4[(unsigned)(s3 * 8 + cg)];
        edge_fma(u0, w_0, acc);
        edge_fma(u1, w_1, acc);
        edge_fma(u2, w_2, acc);
        edge_fma(u3, w_3, acc);
    }
    if (b + 8 <= mcount) {
        int i0 = b + sub, i1 = b + 4 + sub;
        int s0 = __shfl(srcReg, lanebase + i0);
        int s1 = __shfl(srcReg, lanebase + i1);
        float w_0 = __shfl(wReg, lanebase + i0);
        float w_1 = __shfl(wReg, lanebase + i1);
        uint4 u0 = h2v4[(unsigned)(s0 * 8 + cg)];
        uint4 u1 = h2v4[(unsigned)(s1 * 8 + cg)];
        edge_fma(u0, w_0, acc);
        edge_fma(u1, w_1, acc);
        b += 8;
    }
    if (b + 4 <= mcount) {
        int i0 = b + sub;
        int s0 = __shfl(srcReg, lanebase + i0);
        float w_0 = __shfl(wReg, lanebase + i0);
        uint4 u0 = h2v4[(unsigned)(s0 * 8 + cg)];
        edge_fma(u0, w_0, acc);
        b += 4;
    }
    if (b < mcount) {
        int rem = mcount - b;              // 1..3
        int i0 = b + sub;
        int ic = min(i0, mcount - 1);
        int s0 = __shfl(srcReg, lanebase + ic);   // all lanes active at the shfl
        float w_0 = __shfl(wReg, lanebase + ic);
        if (sub < rem) {
            uint4 u0 = h2v4[(unsigned)(s0 * 8 + cg)];
            edge_fma(u0, w_0, acc);
        }
    }
}

__global__ void __launch_bounds__(256)
agg2_kernel(const int* __restrict__ csr, const int* __restrict__ indptr,
            const int* __restrict__ counts, const float* __restrict__ as2,
            const float* __restrict__ ad2, const unsigned short* __restrict__ h2b,
            const float* __restrict__ b2, float* __restrict__ out, int N) {
    int lane = threadIdx.x & 63;
    int l32 = lane & 31;
    int lanebase = lane & 32;
    int n = blockIdx.x * 8 + (threadIdx.x >> 6) * 2 + (lane >> 5);
    if (n >= N) return;
    int start = indptr[n];
    int cnt = counts[n];
    float ad = ad2[n];

    int src0 = 0;
    float p0 = 0.f;
    if (l32 < cnt) {
        src0 = csr[start + l32];
        p0 = __expf(leaky(as2[src0] + ad));   // no max pass
    }
    float l = p0;
    if (cnt > 32) {
        for (int base = 32; base < cnt; base += 32) {
            if (base + l32 < cnt)
                l += __expf(leaky(as2[csr[start + base + l32]] + ad));
        }
    }
#pragma unroll
    for (int off = 16; off >= 1; off >>= 1) l += __shfl_xor(l, off);
    float li = 1.f / l;
    float w0 = p0 * li;

    int sub = l32 >> 3;    // edge within 4-group
    int cg = lane & 7;     // channel group (8 ch each)
    const uint4* h2v4 = (const uint4*)h2b;
    v2f acc[4];
    acc[0] = acc[1] = acc[2] = acc[3] = (v2f){0.f, 0.f};
    accum2(src0, w0, min(cnt, 32), h2v4, lanebase, sub, cg, acc);
    if (cnt > 32) {
        for (int base = 32; base < cnt; base += 32) {
            int srcc = 0;
            float wc = 0.f;
            if (base + l32 < cnt) {
                srcc = csr[start + base + l32];
                wc = __expf(leaky(as2[srcc] + ad)) * li;
            }
            accum2(srcc, wc, min(cnt - base, 32), h2v4, lanebase, sub, cg, acc);
        }
    }
#pragma unroll
    for (int i = 0; i < 4; i++) {
        acc[i].x += __shfl_xor(acc[i].x, 8);
        acc[i].x += __shfl_xor(acc[i].x, 16);
        acc[i].y += __shfl_xor(acc[i].y, 8);
        acc[i].y += __shfl_xor(acc[i].y, 16);
    }
    if (l32 < 8) {
        const float4* b4 = (const float4*)b2;
        float4 ba = b4[cg * 2], bb = b4[cg * 2 + 1];
        float4 o0, o1;
        o0.x = acc[0].x + ba.x; o0.y = acc[0].y + ba.y;
        o0.z = acc[1].x + ba.z; o0.w = acc[1].y + ba.w;
        o1.x = acc[2].x + bb.x; o1.y = acc[2].y + bb.y;
        o1.z = acc[3].x + bb.z; o1.w = acc[3].y + bb.w;
        float4* orow = (float4*)&out[(size_t)n * 64 + cg * 8];
        orow[0] = o0;
        orow[1] = o1;
    }
}

// ---------------- launcher ----------------

extern "C" void kernel_launch(void* const* d_in, const int* in_sizes, int n_in,
                              void* d_out, int out_size, void* d_ws, size_t ws_size,
                              hipStream_t stream) {
    const int*   xidx = (const int*)d_in[0];
    const int*   ei   = (const int*)d_in[1];
    const float* emb  = (const float*)d_in[2];
    const float* W1   = (const float*)d_in[3];
    const float* a_s1 = (const float*)d_in[4];
    const float* a_d1 = (const float*)d_in[5];
    const float* b1   = (const float*)d_in[6];
    const float* W2   = (const float*)d_in[7];
    const float* a_s2 = (const float*)d_in[8];
    const float* a_d2 = (const float*)d_in[9];
    const float* b2   = (const float*)d_in[10];
    float* out = (float*)d_out;

    const int N  = in_sizes[0];
    const int E  = in_sizes[1] / 2;
    const int E2 = E + N;
    const int K  = (N + 255) >> BK_SHIFT;   // 391 buckets for N=100000

    // workspace layout
    int* ws_i    = (int*)d_ws;
    int* counts  = ws_i;                       // N
    int* indptr  = ws_i + N;                   // N
    int* bcounts = ws_i + 2 * (size_t)N;       // 512
    int* bbase   = ws_i + 2 * (size_t)N + 512; // 513
    int* bcursor = ws_i + 2 * (size_t)N + 1032;// 512
    int* csr     = ws_i + 2 * (size_t)N + 1544;// E2
    size_t fbase = ((size_t)(2 * (size_t)N + 1544 + E2) + 3) & ~(size_t)3;
    float* ws_f = (float*)d_ws;
    unsigned short* h1b = (unsigned short*)(ws_f + fbase);   // N*128 bf16 (N*64 floats)
    float* region2 = ws_f + fbase + (size_t)N * 64;          // old-x1b region (N*64 floats)
    unsigned short* h2b = (unsigned short*)region2;          // N*64 bf16 (N*32 floats)
    float* as2 = region2 + (size_t)N * 32;                   // N floats
    float* ad2 = region2 + (size_t)N * 33;                   // N floats
    unsigned short* w2p  = (unsigned short*)(region2 + (size_t)N * 34);          // 8192 ushorts (16KB)
    unsigned short* w1ph = (unsigned short*)(region2 + (size_t)N * 34 + 4096);   // 16384 ushorts (32KB)
    unsigned short* w1pl = (unsigned short*)(region2 + (size_t)N * 34 + 12288);  // 16384 ushorts (32KB)
    float* as1 = ws_f + fbase + (size_t)N * 128;             // N*4
    float* ad1 = as1 + (size_t)N * 4;                        // N*4
    unsigned int* bedges = (unsigned int*)region2;  // alias: dead after bcsr, before agg1 writes

    // prep: W1 hi/lo + W2 B-frag packs + bcounts zero (one dispatch)
    prep_kernel<<<(16384 + 8192 + 512 + 255) / 256, 256, 0, stream>>>(W1, W2, w1ph, w1pl, w2p, bcounts);

    // CSR build: dst-radix partition
    int nchunks = (E2 + 4095) / 4096;
    bcount_kernel<<<nchunks, 256, 0, stream>>>(ei, E, E2, K, bcounts);
    bscan_kernel<<<1, 512, 0, stream>>>(bcounts, K, bbase, bcursor);
    bscatter_kernel<<<nchunks, 256, 0, stream>>>(ei, E, E2, K, bcursor, bedges);
    bcsr_kernel<<<K, 256, 0, stream>>>(bedges, bbase, N, counts, indptr, csr);

    // Layer 1 GEMM on MFMA (bf16x3, fuses alpha1 + bf16 h1)
    gemm1_kernel<<<(N + 127) / 128, 256, 0, stream>>>(emb, xidx, w1ph, w1pl, h1b,
                                                      a_s1, a_d1, as1, ad1, N);

    // agg1 + MFMA-fused gemm2/alpha2 — 512-thread blocks (16 nodes/block)
    agg1_kernel<<<(N + 15) / 16, 512, 0, stream>>>(csr, indptr, counts, as1, ad1, h1b, b1,
                                                   w2p, a_s2, a_d2, h2b, as2, ad2, N);

    // Layer 2 aggregation (r8 form)
    agg2_kernel<<<(N + 7) / 8, 256, 0, stream>>>(csr, indptr, counts, as2, ad2, h2b, b2, out, N);
}